// Round 1
// baseline (216.182 us; speedup 1.0000x reference)
//
#include <hip/hip_runtime.h>

// GCN 2-layer forward, N=100000, E=3200000, 128->16->2.
// Session-2 round-0: verbatim resubmit of the 215.6us harness-verified
// kernel (round-0 bench was an infra failure: GPUAcquisitionTimeout --
// code never ran). Need baseline rocprof before touching anything.
// Validated and kept: binary-search writeback in k_scatter (r6 bmap variant
// faulted), K-split k_xw1, 4-nodes/wave agg kernels, bf16 hs (3.2MB,
// L2-resident), bhist persistence (k_count -> k_scatter).
// Round-7 lesson: LDS-atomic aggregation is 8x worse than sorted gather.
// Algebra: hs = (x@W1)*dinv;
//   h1[d]  = relu(dinv[d]*(sum_nbr hs + hs[d]) + b1), W2 fused -> h2s
//   out[d] = dinv[d]*(sum_nbr h2s + h2s[d]) + b2

#define EPB 8192     // edges per partition block
#define CAP 16384    // LDS slots per bucket in k_fillB (mean 8192, 90 sigma)

typedef unsigned int u32;
typedef unsigned short u16;

__device__ __forceinline__ float bflo(u32 u) { return __uint_as_float(u << 16); }
__device__ __forceinline__ float bfhi(u32 u) { return __uint_as_float(u & 0xffff0000u); }
__device__ __forceinline__ u32 pack_bf2(float a, float b) {   // RNE
    u32 ua = __float_as_uint(a); ua = (ua + 0x7fffu + ((ua >> 16) & 1u)) >> 16;
    u32 ub = __float_as_uint(b); ub = (ub + 0x7fffu + ((ub >> 16) & 1u)) >> 16;
    return ua | (ub << 16);
}

// ---------------- zero bucket counters ----------------
__global__ __launch_bounds__(512) void k_bzero(int* __restrict__ gcnt, int NBUK) {
    int t = threadIdx.x;
    if (t < NBUK) gcnt[t] = 0;
}

// ---------------- bucket histogram; persists per-block rows ----------------
__global__ __launch_bounds__(512) void k_count(const int* __restrict__ dst,
                                               int* __restrict__ gcnt,
                                               u16* __restrict__ bhist,
                                               int E, int NBUK) {
    __shared__ int hist[512];
    int tid = threadIdx.x;
    hist[tid] = 0;
    __syncthreads();
    int base = blockIdx.x * EPB;
    int end = base + EPB; if (end > E) end = E;
    for (int e = base + tid; e < end; e += 512)
        atomicAdd(&hist[dst[e] >> 8], 1);
    __syncthreads();
    int v = hist[tid];
    if (tid < NBUK) {
        if (v) atomicAdd(&gcnt[tid], v);
        bhist[(size_t)blockIdx.x * 512 + tid] = (u16)v;   // row for k_scatter
    }
}

// ---------------- scan bucket counts -> bases (single block) ----------------
__global__ __launch_bounds__(512) void k_bscan(const int* __restrict__ gcnt,
                                               int* __restrict__ gbase,
                                               int* __restrict__ gcur,
                                               int* __restrict__ rp,
                                               int N, int E, int NBUK) {
    __shared__ int s[512];
    int tid = threadIdx.x;
    int v = (tid < NBUK) ? gcnt[tid] : 0;
    s[tid] = v;
    __syncthreads();
    for (int o = 1; o < 512; o <<= 1) {
        int t = (tid >= o) ? s[tid - o] : 0;
        __syncthreads();
        s[tid] += t;
        __syncthreads();
    }
    if (tid < NBUK) { int b = s[tid] - v; gbase[tid] = b; gcur[tid] = b; }
    if (tid == 0) rp[N] = E;
}

// ---------------- partition; histogram loaded from bhist ----------------
__global__ __launch_bounds__(512) void k_scatter(const int* __restrict__ ei,
                                                 const u16* __restrict__ bhist,
                                                 int* __restrict__ gcur,
                                                 u32* __restrict__ part,
                                                 int E, int NBUK) {
    __shared__ int hist[512];   // placement cursors
    __shared__ int lofs[512];   // exclusive offsets (binary-search key)
    __shared__ int rbase[512];  // global addr = rbase[b] + local slot j
    __shared__ u32 buf[EPB];
    int tid = threadIdx.x;
    int v = (tid < NBUK) ? (int)bhist[(size_t)blockIdx.x * 512 + tid] : 0;
    lofs[tid] = v;
    __syncthreads();
    for (int o = 1; o < 512; o <<= 1) {
        int t = (tid >= o) ? lofs[tid - o] : 0;
        __syncthreads();
        lofs[tid] += t;
        __syncthreads();
    }
    int excl = lofs[tid] - v;
    int rb = 0;
    if (tid < NBUK && v > 0) rb = atomicAdd(&gcur[tid], v);  // reserve run
    rbase[tid] = rb - excl;
    hist[tid] = excl;           // placement cursor
    lofs[tid] = excl;           // overwrite scan values with excl (own slot)
    __syncthreads();
    int base = blockIdx.x * EPB;
    int end = base + EPB; if (end > E) end = E;
    for (int e = base + tid; e < end; e += 512) {
        int s = ei[e], d = ei[E + e];
        int pos = atomicAdd(&hist[d >> 8], 1);
        buf[pos] = ((u32)(d & 255) << 24) | (u32)s;          // N < 2^24
    }
    __syncthreads();
    int cnt = end - base;
    for (int j = tid; j < cnt; j += 512) {
        int lo = 0, hi = NBUK - 1;                            // last b: lofs[b] <= j
        while (lo < hi) {
            int mid = (lo + hi + 1) >> 1;
            if (lofs[mid] <= j) lo = mid; else hi = mid - 1;
        }
        part[rbase[lo] + j] = buf[j];                         // ~coalesced runs
    }
}

// ---------------- per-bucket sort by dst; csr in place (512 thr) -------------
__global__ __launch_bounds__(512) void k_fillB(u32* __restrict__ part,
                                               const int* __restrict__ gbase,
                                               const int* __restrict__ gcnt,
                                               int* __restrict__ rp,
                                               float* __restrict__ dinv, int N) {
    __shared__ int hist[256];
    __shared__ int ofs[256];
    __shared__ u32 srcbuf[CAP];
    int b = blockIdx.x, tid = threadIdx.x;
    int base = gbase[b], cnt = gcnt[b];
    if (tid < 256) hist[tid] = 0;
    __syncthreads();
    for (int j = tid; j < cnt; j += 512)
        atomicAdd(&hist[part[base + j] >> 24], 1);
    __syncthreads();
    int v = 0;
    if (tid < 256) { v = hist[tid]; ofs[tid] = v; }
    __syncthreads();
    for (int o = 1; o < 256; o <<= 1) {
        int t = 0;
        if (tid < 256 && tid >= o) t = ofs[tid - o];
        __syncthreads();
        if (tid < 256) ofs[tid] += t;
        __syncthreads();
    }
    int excl = 0;
    if (tid < 256) { excl = ofs[tid] - v; hist[tid] = excl; }
    __syncthreads();
    for (int j = tid; j < cnt; j += 512) {
        u32 pv = part[base + j];
        int pos = atomicAdd(&hist[pv >> 24], 1);
        if (pos < CAP) srcbuf[pos] = pv & 0xFFFFFFu;
    }
    __syncthreads();
    for (int j = tid; j < cnt; j += 512)
        part[base + j] = srcbuf[j];    // coalesced write-back
    int d = b * 256 + tid;
    if (tid < 256 && d < N) {
        rp[d] = base + excl;
        dinv[d] = rsqrtf((float)(v + 1));   // +1 self loop
    }
}

// ---------------- hs[N,16](bf16) = (x@W1)*dinv, K-split, x read once ---------
__global__ __launch_bounds__(256) void k_xw1(const float* __restrict__ x,
                                             const float* __restrict__ W1,
                                             const float* __restrict__ dinv,
                                             u16* __restrict__ hs, int N) {
    __shared__ float w[4 * 516];   // section q = W1 rows 32q..32q+31; +4 pad
    int tid = threadIdx.x;
    for (int t = tid; t < 2048; t += 256)
        w[(t >> 9) * 516 + (t & 511)] = W1[t];
    __syncthreads();
    int t = blockIdx.x * 256 + tid;
    int n = t >> 2, q = t & 3;
    if (n >= N) return;
    const float4* xr = (const float4*)(x + (size_t)n * 128 + q * 32);  // 8 f4
    const float* ws = w + q * 516;
    float acc[16];
    #pragma unroll
    for (int c = 0; c < 16; ++c) acc[c] = 0.f;
    #pragma unroll
    for (int i = 0; i < 8; ++i) {
        float4 u = xr[i];
        const float4* wf = (const float4*)(ws + i * 64);  // rows 4i..4i+3
        #pragma unroll
        for (int c4 = 0; c4 < 4; ++c4) {
            float4 wa = wf[c4];
            float4 wb = wf[4 + c4];
            float4 wc = wf[8 + c4];
            float4 wd = wf[12 + c4];
            int c = c4 * 4;
            acc[c+0] = fmaf(u.x, wa.x, acc[c+0]); acc[c+1] = fmaf(u.x, wa.y, acc[c+1]);
            acc[c+2] = fmaf(u.x, wa.z, acc[c+2]); acc[c+3] = fmaf(u.x, wa.w, acc[c+3]);
            acc[c+0] = fmaf(u.y, wb.x, acc[c+0]); acc[c+1] = fmaf(u.y, wb.y, acc[c+1]);
            acc[c+2] = fmaf(u.y, wb.z, acc[c+2]); acc[c+3] = fmaf(u.y, wb.w, acc[c+3]);
            acc[c+0] = fmaf(u.z, wc.x, acc[c+0]); acc[c+1] = fmaf(u.z, wc.y, acc[c+1]);
            acc[c+2] = fmaf(u.z, wc.z, acc[c+2]); acc[c+3] = fmaf(u.z, wc.w, acc[c+3]);
            acc[c+0] = fmaf(u.w, wd.x, acc[c+0]); acc[c+1] = fmaf(u.w, wd.y, acc[c+1]);
            acc[c+2] = fmaf(u.w, wd.z, acc[c+2]); acc[c+3] = fmaf(u.w, wd.w, acc[c+3]);
        }
    }
    #pragma unroll
    for (int c = 0; c < 16; ++c) {
        acc[c] += __shfl_xor(acc[c], 1);
        acc[c] += __shfl_xor(acc[c], 2);
    }
    float di = dinv[n];
    uint2 o;
    o.x = pack_bf2(acc[4*q+0] * di, acc[4*q+1] * di);
    o.y = pack_bf2(acc[4*q+2] * di, acc[4*q+3] * di);
    ((uint2*)(hs + (size_t)n * 16))[q] = o;
}

// ---------------- fused layer-1 gather + ReLU + W2 projection ----------------
// 4 nodes/wave; 16 lanes/node = 4 lanes/row (uint2 each) x 4 edge groups.
__global__ __launch_bounds__(256) void k_agg1h2(const int* __restrict__ rp,
                                                const int* __restrict__ csr,
                                                const u16* __restrict__ hs,
                                                const float* __restrict__ dinv,
                                                const float* __restrict__ W2,
                                                const float* __restrict__ b1,
                                                float* __restrict__ h2s, int N) {
    int lane = threadIdx.x & 63;
    int wid = blockIdx.x * 16 + (threadIdx.x >> 6) * 4 + (lane >> 4);
    if (wid >= N) return;
    int l = lane & 15;
    int c4 = l & 3, g = l >> 2;                    // channel quad, edge group
    int beg = rp[wid], end = rp[wid + 1];
    float ax = 0.f, ay = 0.f, az = 0.f, aw = 0.f;
    for (int j = beg + g; j < end; j += 4) {
        int s = csr[j];
        uint2 u = ((const uint2*)(hs + (size_t)s * 16))[c4];
        ax += bflo(u.x); ay += bfhi(u.x);
        az += bflo(u.y); aw += bfhi(u.y);
    }
    ax += __shfl_xor(ax, 4); ay += __shfl_xor(ay, 4);
    az += __shfl_xor(az, 4); aw += __shfl_xor(aw, 4);
    ax += __shfl_xor(ax, 8); ay += __shfl_xor(ay, 8);
    az += __shfl_xor(az, 8); aw += __shfl_xor(aw, 8);
    uint2 su = ((const uint2*)(hs + (size_t)wid * 16))[c4];   // self term
    ax += bflo(su.x); ay += bfhi(su.x);
    az += bflo(su.y); aw += bfhi(su.y);
    float di = dinv[wid];
    float4 bq = ((const float4*)b1)[c4];
    float vx = fmaxf(fmaf(di, ax, bq.x), 0.f);
    float vy = fmaxf(fmaf(di, ay, bq.y), 0.f);
    float vz = fmaxf(fmaf(di, az, bq.z), 0.f);
    float vw = fmaxf(fmaf(di, aw, bq.w), 0.f);
    float4 pa = ((const float4*)W2)[2 * c4];
    float4 pb = ((const float4*)W2)[2 * c4 + 1];
    float p0 = vx * pa.x + vy * pa.z + vz * pb.x + vw * pb.z;
    float p1 = vx * pa.y + vy * pa.w + vz * pb.y + vw * pb.w;
    p0 += __shfl_xor(p0, 1); p1 += __shfl_xor(p1, 1);
    p0 += __shfl_xor(p0, 2); p1 += __shfl_xor(p1, 2);
    if (l == 0)
        *(float2*)(h2s + (size_t)wid * 2) = make_float2(p0 * di, p1 * di);
}

// ---------------- layer-2 gather -> out (4 nodes/wave, 16 lanes/node) --------
__global__ __launch_bounds__(256) void k_agg2(const int* __restrict__ rp,
                                              const int* __restrict__ csr,
                                              const float* __restrict__ h2s,
                                              const float* __restrict__ dinv,
                                              const float* __restrict__ b2,
                                              float* __restrict__ out, int N) {
    int lane = threadIdx.x & 63;
    int wid = blockIdx.x * 16 + (threadIdx.x >> 6) * 4 + (lane >> 4);
    if (wid >= N) return;
    int l = lane & 15;
    int beg = rp[wid], end = rp[wid + 1];
    float a0 = 0.f, a1 = 0.f;
    for (int j = beg + l; j < end; j += 16) {
        int s = csr[j];
        float2 v = *(const float2*)(h2s + (size_t)s * 2);
        a0 += v.x; a1 += v.y;
    }
    a0 += __shfl_xor(a0, 1); a1 += __shfl_xor(a1, 1);
    a0 += __shfl_xor(a0, 2); a1 += __shfl_xor(a1, 2);
    a0 += __shfl_xor(a0, 4); a1 += __shfl_xor(a1, 4);
    a0 += __shfl_xor(a0, 8); a1 += __shfl_xor(a1, 8);
    if (l == 0) {
        float di = dinv[wid];
        float2 sv = *(const float2*)(h2s + (size_t)wid * 2);
        *(float2*)(out + (size_t)wid * 2) =
            make_float2(fmaf(di, a0 + sv.x, b2[0]), fmaf(di, a1 + sv.y, b2[1]));
    }
}

extern "C" void kernel_launch(void* const* d_in, const int* in_sizes, int n_in,
                              void* d_out, int out_size, void* d_ws, size_t ws_size,
                              hipStream_t stream) {
    const float* x  = (const float*)d_in[0];
    const int*   ei = (const int*)d_in[1];
    const float* W1 = (const float*)d_in[2];
    const float* b1 = (const float*)d_in[3];
    const float* W2 = (const float*)d_in[4];
    const float* b2 = (const float*)d_in[5];
    float* out = (float*)d_out;

    const int N = in_sizes[0] / 128;      // 100000
    const int E = in_sizes[1] / 2;        // 3200000
    const int NBUK = (N + 255) / 256;     // 391 (<= 512)
    const int NPB  = (E + EPB - 1) / EPB; // 391

    char* ws = (char*)d_ws;
    size_t off = 0;
    auto alloc = [&](size_t bytes) {
        void* p = ws + off;
        off = (off + bytes + 255) & ~(size_t)255;
        return p;
    };
    u32*   part  = (u32*)alloc((size_t)E * 4);       // partition buf == csr
    int*   rp    = (int*)alloc((size_t)(N + 1) * 4);
    float* dinv  = (float*)alloc((size_t)N * 4);
    u16*   hs    = (u16*)alloc((size_t)N * 16 * 2);  // bf16
    float* h2s   = (float*)alloc((size_t)N * 2 * 4);
    int*   gcnt  = (int*)alloc((size_t)NBUK * 4);
    int*   gbase = (int*)alloc((size_t)NBUK * 4);
    int*   gcur  = (int*)alloc((size_t)NBUK * 4);
    u16*   bhist = (u16*)alloc((size_t)NPB * 512 * 2);

    k_bzero  <<<dim3(1),    dim3(512), 0, stream>>>(gcnt, NBUK);
    k_count  <<<dim3(NPB),  dim3(512), 0, stream>>>(ei + E, gcnt, bhist, E, NBUK);
    k_bscan  <<<dim3(1),    dim3(512), 0, stream>>>(gcnt, gbase, gcur, rp, N, E, NBUK);
    k_scatter<<<dim3(NPB),  dim3(512), 0, stream>>>(ei, bhist, gcur, part, E, NBUK);
    k_fillB  <<<dim3(NBUK), dim3(512), 0, stream>>>(part, gbase, gcnt, rp, dinv, N);
    k_xw1    <<<dim3((N * 4 + 255) / 256), dim3(256), 0, stream>>>(x, W1, dinv, hs, N);
    k_agg1h2 <<<dim3((N + 15) / 16), dim3(256), 0, stream>>>(rp, (const int*)part, hs, dinv, W2, b1, h2s, N);
    k_agg2   <<<dim3((N + 15) / 16), dim3(256), 0, stream>>>(rp, (const int*)part, h2s, dinv, b2, out, N);
}

// Round 2
// 201.369 us; speedup vs baseline: 1.0736x; 1.0736x over previous
//
#include <hip/hip_runtime.h>

// GCN 2-layer forward, N=100000, E=3200000, 128->16->2.
// Session-2 round-1 (baseline 216.2us verified, counters show only harness
// memsets at 6.5TB/s -- our kernels all <41us, invisible to top-k).
// Changes vs baseline, each with independent theory:
//  - k_scatter: binary-search writeback (9 dep LDS reads/elem) replaced by
//    u16 bkt[] LDS array written at atomic-placement time (1 LDS read/elem).
//    lofs[] dropped; LDS 52KB -> 3 blocks/CU.
//  - k_count/k_scatter: int4-vectorized edge reads (4 edges/lane/instr).
//  - k_agg1h2: hs gather restructured 4x8B -> 2x16B per edge (2 halves x
//    8 edge groups); halves L2 request count and dependent-chain depth.
// Validated and kept: K-split k_xw1, 4-nodes/wave agg kernels, bf16 hs
// (3.2MB, L2-resident), bhist persistence (k_count -> k_scatter).
// Round-7 lesson: LDS-atomic aggregation is 8x worse than sorted gather.
// Algebra: hs = (x@W1)*dinv;
//   h1[d]  = relu(dinv[d]*(sum_nbr hs + hs[d]) + b1), W2 fused -> h2s
//   out[d] = dinv[d]*(sum_nbr h2s + h2s[d]) + b2

#define EPB 8192     // edges per partition block
#define CAP 16384    // LDS slots per bucket in k_fillB (mean 8192, 90 sigma)

typedef unsigned int u32;
typedef unsigned short u16;

__device__ __forceinline__ float bflo(u32 u) { return __uint_as_float(u << 16); }
__device__ __forceinline__ float bfhi(u32 u) { return __uint_as_float(u & 0xffff0000u); }
__device__ __forceinline__ u32 pack_bf2(float a, float b) {   // RNE
    u32 ua = __float_as_uint(a); ua = (ua + 0x7fffu + ((ua >> 16) & 1u)) >> 16;
    u32 ub = __float_as_uint(b); ub = (ub + 0x7fffu + ((ub >> 16) & 1u)) >> 16;
    return ua | (ub << 16);
}

// ---------------- zero bucket counters ----------------
__global__ __launch_bounds__(512) void k_bzero(int* __restrict__ gcnt, int NBUK) {
    int t = threadIdx.x;
    if (t < NBUK) gcnt[t] = 0;
}

// ---------------- bucket histogram; persists per-block rows ----------------
__global__ __launch_bounds__(512) void k_count(const int* __restrict__ dst,
                                               int* __restrict__ gcnt,
                                               u16* __restrict__ bhist,
                                               int E, int NBUK) {
    __shared__ int hist[512];
    int tid = threadIdx.x;
    hist[tid] = 0;
    __syncthreads();
    int base = blockIdx.x * EPB;
    int end = base + EPB; if (end > E) end = E;
    int cnt = end - base;
    int nv = cnt >> 2;
    const int4* d4p = (const int4*)(dst + base);
    for (int t = tid; t < nv; t += 512) {
        int4 d4 = d4p[t];
        atomicAdd(&hist[d4.x >> 8], 1);
        atomicAdd(&hist[d4.y >> 8], 1);
        atomicAdd(&hist[d4.z >> 8], 1);
        atomicAdd(&hist[d4.w >> 8], 1);
    }
    for (int e = base + (nv << 2) + tid; e < end; e += 512)
        atomicAdd(&hist[dst[e] >> 8], 1);
    __syncthreads();
    int v = hist[tid];
    if (tid < NBUK) {
        if (v) atomicAdd(&gcnt[tid], v);
        bhist[(size_t)blockIdx.x * 512 + tid] = (u16)v;   // row for k_scatter
    }
}

// ---------------- scan bucket counts -> bases (single block) ----------------
__global__ __launch_bounds__(512) void k_bscan(const int* __restrict__ gcnt,
                                               int* __restrict__ gbase,
                                               int* __restrict__ gcur,
                                               int* __restrict__ rp,
                                               int N, int E, int NBUK) {
    __shared__ int s[512];
    int tid = threadIdx.x;
    int v = (tid < NBUK) ? gcnt[tid] : 0;
    s[tid] = v;
    __syncthreads();
    for (int o = 1; o < 512; o <<= 1) {
        int t = (tid >= o) ? s[tid - o] : 0;
        __syncthreads();
        s[tid] += t;
        __syncthreads();
    }
    if (tid < NBUK) { int b = s[tid] - v; gbase[tid] = b; gcur[tid] = b; }
    if (tid == 0) rp[N] = E;
}

// ---------------- partition; histogram loaded from bhist ----------------
// bkt[] remembers each staged element's bucket so the writeback is a single
// LDS read instead of a 9-iteration binary search.
__global__ __launch_bounds__(512) void k_scatter(const int* __restrict__ ei,
                                                 const u16* __restrict__ bhist,
                                                 int* __restrict__ gcur,
                                                 u32* __restrict__ part,
                                                 int E, int NBUK) {
    __shared__ int hist[512];   // scan buffer, then placement cursors
    __shared__ int rbase[512];  // global addr = rbase[b] + local slot j
    __shared__ u32 buf[EPB];
    __shared__ u16 bkt[EPB];
    int tid = threadIdx.x;
    int v = (tid < NBUK) ? (int)bhist[(size_t)blockIdx.x * 512 + tid] : 0;
    hist[tid] = v;
    __syncthreads();
    for (int o = 1; o < 512; o <<= 1) {
        int t = (tid >= o) ? hist[tid - o] : 0;
        __syncthreads();
        hist[tid] += t;
        __syncthreads();
    }
    int excl = hist[tid] - v;
    int rb = 0;
    if (tid < NBUK && v > 0) rb = atomicAdd(&gcur[tid], v);  // reserve run
    rbase[tid] = rb - excl;
    hist[tid] = excl;           // placement cursor (own slot only -> no race)
    __syncthreads();
    int base = blockIdx.x * EPB;
    int end = base + EPB; if (end > E) end = E;
    int cnt = end - base;
    int nv = cnt >> 2;
    const int4* s4p = (const int4*)(ei + base);
    const int4* d4p = (const int4*)(ei + E + base);
    for (int t = tid; t < nv; t += 512) {
        int4 s4 = s4p[t];
        int4 d4 = d4p[t];
        int b, pos;
        b = d4.x >> 8; pos = atomicAdd(&hist[b], 1);
        buf[pos] = ((u32)(d4.x & 255) << 24) | (u32)s4.x; bkt[pos] = (u16)b;
        b = d4.y >> 8; pos = atomicAdd(&hist[b], 1);
        buf[pos] = ((u32)(d4.y & 255) << 24) | (u32)s4.y; bkt[pos] = (u16)b;
        b = d4.z >> 8; pos = atomicAdd(&hist[b], 1);
        buf[pos] = ((u32)(d4.z & 255) << 24) | (u32)s4.z; bkt[pos] = (u16)b;
        b = d4.w >> 8; pos = atomicAdd(&hist[b], 1);
        buf[pos] = ((u32)(d4.w & 255) << 24) | (u32)s4.w; bkt[pos] = (u16)b;
    }
    for (int e = base + (nv << 2) + tid; e < end; e += 512) {
        int s = ei[e], d = ei[E + e];
        int b = d >> 8;
        int pos = atomicAdd(&hist[b], 1);
        buf[pos] = ((u32)(d & 255) << 24) | (u32)s;
        bkt[pos] = (u16)b;
    }
    __syncthreads();
    for (int j = tid; j < cnt; j += 512)
        part[rbase[bkt[j]] + j] = buf[j];                 // ~coalesced runs
}

// ---------------- per-bucket sort by dst; csr in place (512 thr) -------------
__global__ __launch_bounds__(512) void k_fillB(u32* __restrict__ part,
                                               const int* __restrict__ gbase,
                                               const int* __restrict__ gcnt,
                                               int* __restrict__ rp,
                                               float* __restrict__ dinv, int N) {
    __shared__ int hist[256];
    __shared__ int ofs[256];
    __shared__ u32 srcbuf[CAP];
    int b = blockIdx.x, tid = threadIdx.x;
    int base = gbase[b], cnt = gcnt[b];
    if (tid < 256) hist[tid] = 0;
    __syncthreads();
    for (int j = tid; j < cnt; j += 512)
        atomicAdd(&hist[part[base + j] >> 24], 1);
    __syncthreads();
    int v = 0;
    if (tid < 256) { v = hist[tid]; ofs[tid] = v; }
    __syncthreads();
    for (int o = 1; o < 256; o <<= 1) {
        int t = 0;
        if (tid < 256 && tid >= o) t = ofs[tid - o];
        __syncthreads();
        if (tid < 256) ofs[tid] += t;
        __syncthreads();
    }
    int excl = 0;
    if (tid < 256) { excl = ofs[tid] - v; hist[tid] = excl; }
    __syncthreads();
    for (int j = tid; j < cnt; j += 512) {
        u32 pv = part[base + j];
        int pos = atomicAdd(&hist[pv >> 24], 1);
        if (pos < CAP) srcbuf[pos] = pv & 0xFFFFFFu;
    }
    __syncthreads();
    for (int j = tid; j < cnt; j += 512)
        part[base + j] = srcbuf[j];    // coalesced write-back
    int d = b * 256 + tid;
    if (tid < 256 && d < N) {
        rp[d] = base + excl;
        dinv[d] = rsqrtf((float)(v + 1));   // +1 self loop
    }
}

// ---------------- hs[N,16](bf16) = (x@W1)*dinv, K-split, x read once ---------
__global__ __launch_bounds__(256) void k_xw1(const float* __restrict__ x,
                                             const float* __restrict__ W1,
                                             const float* __restrict__ dinv,
                                             u16* __restrict__ hs, int N) {
    __shared__ float w[4 * 516];   // section q = W1 rows 32q..32q+31; +4 pad
    int tid = threadIdx.x;
    for (int t = tid; t < 2048; t += 256)
        w[(t >> 9) * 516 + (t & 511)] = W1[t];
    __syncthreads();
    int t = blockIdx.x * 256 + tid;
    int n = t >> 2, q = t & 3;
    if (n >= N) return;
    const float4* xr = (const float4*)(x + (size_t)n * 128 + q * 32);  // 8 f4
    const float* ws = w + q * 516;
    float acc[16];
    #pragma unroll
    for (int c = 0; c < 16; ++c) acc[c] = 0.f;
    #pragma unroll
    for (int i = 0; i < 8; ++i) {
        float4 u = xr[i];
        const float4* wf = (const float4*)(ws + i * 64);  // rows 4i..4i+3
        #pragma unroll
        for (int c4 = 0; c4 < 4; ++c4) {
            float4 wa = wf[c4];
            float4 wb = wf[4 + c4];
            float4 wc = wf[8 + c4];
            float4 wd = wf[12 + c4];
            int c = c4 * 4;
            acc[c+0] = fmaf(u.x, wa.x, acc[c+0]); acc[c+1] = fmaf(u.x, wa.y, acc[c+1]);
            acc[c+2] = fmaf(u.x, wa.z, acc[c+2]); acc[c+3] = fmaf(u.x, wa.w, acc[c+3]);
            acc[c+0] = fmaf(u.y, wb.x, acc[c+0]); acc[c+1] = fmaf(u.y, wb.y, acc[c+1]);
            acc[c+2] = fmaf(u.y, wb.z, acc[c+2]); acc[c+3] = fmaf(u.y, wb.w, acc[c+3]);
            acc[c+0] = fmaf(u.z, wc.x, acc[c+0]); acc[c+1] = fmaf(u.z, wc.y, acc[c+1]);
            acc[c+2] = fmaf(u.z, wc.z, acc[c+2]); acc[c+3] = fmaf(u.z, wc.w, acc[c+3]);
            acc[c+0] = fmaf(u.w, wd.x, acc[c+0]); acc[c+1] = fmaf(u.w, wd.y, acc[c+1]);
            acc[c+2] = fmaf(u.w, wd.z, acc[c+2]); acc[c+3] = fmaf(u.w, wd.w, acc[c+3]);
        }
    }
    #pragma unroll
    for (int c = 0; c < 16; ++c) {
        acc[c] += __shfl_xor(acc[c], 1);
        acc[c] += __shfl_xor(acc[c], 2);
    }
    float di = dinv[n];
    uint2 o;
    o.x = pack_bf2(acc[4*q+0] * di, acc[4*q+1] * di);
    o.y = pack_bf2(acc[4*q+2] * di, acc[4*q+3] * di);
    ((uint2*)(hs + (size_t)n * 16))[q] = o;
}

// ---------------- fused layer-1 gather + ReLU + W2 projection ----------------
// 4 nodes/wave; 16 lanes/node = 2 halves (16B uint4 each) x 8 edge groups.
// 2x16B per edge instead of 4x8B: halves L2 request count + chain depth.
__global__ __launch_bounds__(256) void k_agg1h2(const int* __restrict__ rp,
                                                const int* __restrict__ csr,
                                                const u16* __restrict__ hs,
                                                const float* __restrict__ dinv,
                                                const float* __restrict__ W2,
                                                const float* __restrict__ b1,
                                                float* __restrict__ h2s, int N) {
    int lane = threadIdx.x & 63;
    int wid = blockIdx.x * 16 + (threadIdx.x >> 6) * 4 + (lane >> 4);
    if (wid >= N) return;
    int l = lane & 15;
    int half = l & 1, g = l >> 1;                  // 16B half, edge group
    int beg = rp[wid], end = rp[wid + 1];
    float a0 = 0.f, a1 = 0.f, a2 = 0.f, a3 = 0.f;
    float a4 = 0.f, a5 = 0.f, a6 = 0.f, a7 = 0.f;
    for (int j = beg + g; j < end; j += 8) {
        int s = csr[j];
        uint4 u = ((const uint4*)(hs + (size_t)s * 16))[half];
        a0 += bflo(u.x); a1 += bfhi(u.x);
        a2 += bflo(u.y); a3 += bfhi(u.y);
        a4 += bflo(u.z); a5 += bfhi(u.z);
        a6 += bflo(u.w); a7 += bfhi(u.w);
    }
    // reduce across the 8 edge groups (lane bits 1..3)
    a0 += __shfl_xor(a0, 2); a1 += __shfl_xor(a1, 2);
    a2 += __shfl_xor(a2, 2); a3 += __shfl_xor(a3, 2);
    a4 += __shfl_xor(a4, 2); a5 += __shfl_xor(a5, 2);
    a6 += __shfl_xor(a6, 2); a7 += __shfl_xor(a7, 2);
    a0 += __shfl_xor(a0, 4); a1 += __shfl_xor(a1, 4);
    a2 += __shfl_xor(a2, 4); a3 += __shfl_xor(a3, 4);
    a4 += __shfl_xor(a4, 4); a5 += __shfl_xor(a5, 4);
    a6 += __shfl_xor(a6, 4); a7 += __shfl_xor(a7, 4);
    a0 += __shfl_xor(a0, 8); a1 += __shfl_xor(a1, 8);
    a2 += __shfl_xor(a2, 8); a3 += __shfl_xor(a3, 8);
    a4 += __shfl_xor(a4, 8); a5 += __shfl_xor(a5, 8);
    a6 += __shfl_xor(a6, 8); a7 += __shfl_xor(a7, 8);
    uint4 su = ((const uint4*)(hs + (size_t)wid * 16))[half];   // self term
    a0 += bflo(su.x); a1 += bfhi(su.x);
    a2 += bflo(su.y); a3 += bfhi(su.y);
    a4 += bflo(su.z); a5 += bfhi(su.z);
    a6 += bflo(su.w); a7 += bfhi(su.w);
    float di = dinv[wid];
    float4 bA = ((const float4*)b1)[half * 2];
    float4 bB = ((const float4*)b1)[half * 2 + 1];
    float v0 = fmaxf(fmaf(di, a0, bA.x), 0.f);
    float v1 = fmaxf(fmaf(di, a1, bA.y), 0.f);
    float v2 = fmaxf(fmaf(di, a2, bA.z), 0.f);
    float v3 = fmaxf(fmaf(di, a3, bA.w), 0.f);
    float v4 = fmaxf(fmaf(di, a4, bB.x), 0.f);
    float v5 = fmaxf(fmaf(di, a5, bB.y), 0.f);
    float v6 = fmaxf(fmaf(di, a6, bB.z), 0.f);
    float v7 = fmaxf(fmaf(di, a7, bB.w), 0.f);
    const float4* w4 = (const float4*)W2 + half * 4;   // rows half*8..+7
    float4 q0 = w4[0], q1 = w4[1], q2 = w4[2], q3 = w4[3];
    float p0 = v0*q0.x + v1*q0.z + v2*q1.x + v3*q1.z
             + v4*q2.x + v5*q2.z + v6*q3.x + v7*q3.z;
    float p1 = v0*q0.y + v1*q0.w + v2*q1.y + v3*q1.w
             + v4*q2.y + v5*q2.w + v6*q3.y + v7*q3.w;
    p0 += __shfl_xor(p0, 1); p1 += __shfl_xor(p1, 1);  // sum the two halves
    if (l == 0)
        *(float2*)(h2s + (size_t)wid * 2) = make_float2(p0 * di, p1 * di);
}

// ---------------- layer-2 gather -> out (4 nodes/wave, 16 lanes/node) --------
__global__ __launch_bounds__(256) void k_agg2(const int* __restrict__ rp,
                                              const int* __restrict__ csr,
                                              const float* __restrict__ h2s,
                                              const float* __restrict__ dinv,
                                              const float* __restrict__ b2,
                                              float* __restrict__ out, int N) {
    int lane = threadIdx.x & 63;
    int wid = blockIdx.x * 16 + (threadIdx.x >> 6) * 4 + (lane >> 4);
    if (wid >= N) return;
    int l = lane & 15;
    int beg = rp[wid], end = rp[wid + 1];
    float a0 = 0.f, a1 = 0.f;
    for (int j = beg + l; j < end; j += 16) {
        int s = csr[j];
        float2 v = *(const float2*)(h2s + (size_t)s * 2);
        a0 += v.x; a1 += v.y;
    }
    a0 += __shfl_xor(a0, 1); a1 += __shfl_xor(a1, 1);
    a0 += __shfl_xor(a0, 2); a1 += __shfl_xor(a1, 2);
    a0 += __shfl_xor(a0, 4); a1 += __shfl_xor(a1, 4);
    a0 += __shfl_xor(a0, 8); a1 += __shfl_xor(a1, 8);
    if (l == 0) {
        float di = dinv[wid];
        float2 sv = *(const float2*)(h2s + (size_t)wid * 2);
        *(float2*)(out + (size_t)wid * 2) =
            make_float2(fmaf(di, a0 + sv.x, b2[0]), fmaf(di, a1 + sv.y, b2[1]));
    }
}

extern "C" void kernel_launch(void* const* d_in, const int* in_sizes, int n_in,
                              void* d_out, int out_size, void* d_ws, size_t ws_size,
                              hipStream_t stream) {
    const float* x  = (const float*)d_in[0];
    const int*   ei = (const int*)d_in[1];
    const float* W1 = (const float*)d_in[2];
    const float* b1 = (const float*)d_in[3];
    const float* W2 = (const float*)d_in[4];
    const float* b2 = (const float*)d_in[5];
    float* out = (float*)d_out;

    const int N = in_sizes[0] / 128;      // 100000
    const int E = in_sizes[1] / 2;        // 3200000
    const int NBUK = (N + 255) / 256;     // 391 (<= 512)
    const int NPB  = (E + EPB - 1) / EPB; // 391

    char* ws = (char*)d_ws;
    size_t off = 0;
    auto alloc = [&](size_t bytes) {
        void* p = ws + off;
        off = (off + bytes + 255) & ~(size_t)255;
        return p;
    };
    u32*   part  = (u32*)alloc((size_t)E * 4);       // partition buf == csr
    int*   rp    = (int*)alloc((size_t)(N + 1) * 4);
    float* dinv  = (float*)alloc((size_t)N * 4);
    u16*   hs    = (u16*)alloc((size_t)N * 16 * 2);  // bf16
    float* h2s   = (float*)alloc((size_t)N * 2 * 4);
    int*   gcnt  = (int*)alloc((size_t)NBUK * 4);
    int*   gbase = (int*)alloc((size_t)NBUK * 4);
    int*   gcur  = (int*)alloc((size_t)NBUK * 4);
    u16*   bhist = (u16*)alloc((size_t)NPB * 512 * 2);

    k_bzero  <<<dim3(1),    dim3(512), 0, stream>>>(gcnt, NBUK);
    k_count  <<<dim3(NPB),  dim3(512), 0, stream>>>(ei + E, gcnt, bhist, E, NBUK);
    k_bscan  <<<dim3(1),    dim3(512), 0, stream>>>(gcnt, gbase, gcur, rp, N, E, NBUK);
    k_scatter<<<dim3(NPB),  dim3(512), 0, stream>>>(ei, bhist, gcur, part, E, NBUK);
    k_fillB  <<<dim3(NBUK), dim3(512), 0, stream>>>(part, gbase, gcnt, rp, dinv, N);
    k_xw1    <<<dim3((N * 4 + 255) / 256), dim3(256), 0, stream>>>(x, W1, dinv, hs, N);
    k_agg1h2 <<<dim3((N + 15) / 16), dim3(256), 0, stream>>>(rp, (const int*)part, hs, dinv, W2, b1, h2s, N);
    k_agg2   <<<dim3((N + 15) / 16), dim3(256), 0, stream>>>(rp, (const int*)part, h2s, dinv, b2, out, N);
}

// Round 4
// 192.081 us; speedup vs baseline: 1.1255x; 1.0484x over previous
//
#include <hip/hip_runtime.h>

// GCN 2-layer forward, N=100000, E=3200000, 128->16->2.
// Session-2 round-3: verbatim resubmit of round-2 source (round-3 bench was
// an infra failure: GPUAcquisitionTimeout -- code never ran; need the
// measurement before stacking further changes).
// Round-2 change under test: eliminate k_count + bhist entirely. Buckets get
// fixed-stride regions in part (RCAP=12288, mean 8192, 45-sigma headroom);
// k_scatter stages its 16 edges/thread in REGISTERS, counts its own local
// histogram, reserves global runs via gcur (init b*RCAP), places, writes.
// k_bscan recovers counts = gcur[b]-b*RCAP, scans to dense bases.
// k_fillB reads region, sorts, writes DENSE csr to a separate buffer
// (in-place would race: dense range of block b overlaps lower regions).
// 8 launches -> 7; one full 12.8MB dst pass + bhist round-trip removed.
// Validated and kept: register/bkt writeback in scatter, K-split k_xw1,
// 4-nodes/wave agg kernels, bf16 hs (3.2MB, L2-resident).
// Round-7 lesson (prev session): LDS-atomic aggregation 8x worse than gather.
// Algebra: hs = (x@W1)*dinv;
//   h1[d]  = relu(dinv[d]*(sum_nbr hs + hs[d]) + b1), W2 fused -> h2s
//   out[d] = dinv[d]*(sum_nbr h2s + h2s[d]) + b2

#define EPB  8192    // edges per partition block
#define RCAP 12288   // per-bucket region capacity (mean 8192, sigma~90)
#define CAP  16384   // LDS slots per bucket in k_fillB

typedef unsigned int u32;
typedef unsigned short u16;

__device__ __forceinline__ float bflo(u32 u) { return __uint_as_float(u << 16); }
__device__ __forceinline__ float bfhi(u32 u) { return __uint_as_float(u & 0xffff0000u); }
__device__ __forceinline__ u32 pack_bf2(float a, float b) {   // RNE
    u32 ua = __float_as_uint(a); ua = (ua + 0x7fffu + ((ua >> 16) & 1u)) >> 16;
    u32 ub = __float_as_uint(b); ub = (ub + 0x7fffu + ((ub >> 16) & 1u)) >> 16;
    return ua | (ub << 16);
}

// ---------------- init bucket region cursors ----------------
__global__ __launch_bounds__(512) void k_binit(int* __restrict__ gcur, int NBUK) {
    int t = threadIdx.x;
    if (t < NBUK) gcur[t] = t * RCAP;
}

// ---------------- single-pass partition: count+scan+reserve+place ----------
// Edges staged in registers (8x int4) across the scan -> no second global read.
__global__ __launch_bounds__(512) void k_scatter(const int* __restrict__ ei,
                                                 int* __restrict__ gcur,
                                                 u32* __restrict__ part,
                                                 int E, int NBUK) {
    __shared__ int hist[512];   // counts -> scan -> placement cursors
    __shared__ int rbase[512];  // global addr = rbase[b] + local slot j
    __shared__ u32 buf[EPB];
    __shared__ u16 bkt[EPB];
    int tid = threadIdx.x;
    hist[tid] = 0;
    __syncthreads();
    int base = blockIdx.x * EPB;
    int end = base + EPB; if (end > E) end = E;
    int cnt = end - base;
    int nv = cnt >> 2;
    const int4* s4p = (const int4*)(ei + base);
    const int4* d4p = (const int4*)(ei + E + base);
    int4 s4[4], d4[4];
    #pragma unroll
    for (int k = 0; k < 4; ++k) {
        int idx = tid + (k << 9);
        if (idx < nv) {
            s4[k] = s4p[idx];
            d4[k] = d4p[idx];
            atomicAdd(&hist[d4[k].x >> 8], 1);
            atomicAdd(&hist[d4[k].y >> 8], 1);
            atomicAdd(&hist[d4[k].z >> 8], 1);
            atomicAdd(&hist[d4[k].w >> 8], 1);
        }
    }
    for (int e = base + (nv << 2) + tid; e < end; e += 512)   // tail (cnt%4)
        atomicAdd(&hist[ei[E + e] >> 8], 1);
    __syncthreads();
    int v = hist[tid];
    __syncthreads();
    for (int o = 1; o < 512; o <<= 1) {                       // in-place scan
        int t = (tid >= o) ? hist[tid - o] : 0;
        __syncthreads();
        hist[tid] += t;
        __syncthreads();
    }
    int excl = hist[tid] - v;
    int rb = 0;
    if (tid < NBUK && v > 0) rb = atomicAdd(&gcur[tid], v);   // reserve run
    rbase[tid] = rb - excl;
    __syncthreads();
    hist[tid] = excl;            // placement cursor (own slot only)
    __syncthreads();
    #pragma unroll
    for (int k = 0; k < 4; ++k) {
        int idx = tid + (k << 9);
        if (idx < nv) {
            int b, pos;
            b = d4[k].x >> 8; pos = atomicAdd(&hist[b], 1);
            buf[pos] = ((u32)(d4[k].x & 255) << 24) | (u32)s4[k].x; bkt[pos] = (u16)b;
            b = d4[k].y >> 8; pos = atomicAdd(&hist[b], 1);
            buf[pos] = ((u32)(d4[k].y & 255) << 24) | (u32)s4[k].y; bkt[pos] = (u16)b;
            b = d4[k].z >> 8; pos = atomicAdd(&hist[b], 1);
            buf[pos] = ((u32)(d4[k].z & 255) << 24) | (u32)s4[k].z; bkt[pos] = (u16)b;
            b = d4[k].w >> 8; pos = atomicAdd(&hist[b], 1);
            buf[pos] = ((u32)(d4[k].w & 255) << 24) | (u32)s4[k].w; bkt[pos] = (u16)b;
        }
    }
    for (int e = base + (nv << 2) + tid; e < end; e += 512) { // tail re-read
        int s = ei[e], d = ei[E + e];
        int b = d >> 8;
        int pos = atomicAdd(&hist[b], 1);
        buf[pos] = ((u32)(d & 255) << 24) | (u32)s;
        bkt[pos] = (u16)b;
    }
    __syncthreads();
    for (int j = tid; j < cnt; j += 512)
        part[rbase[bkt[j]] + j] = buf[j];                     // ~coalesced runs
}

// ---------------- counts from cursors; scan -> dense bases ----------------
__global__ __launch_bounds__(512) void k_bscan(const int* __restrict__ gcur,
                                               int* __restrict__ gcnt,
                                               int* __restrict__ gbase,
                                               int* __restrict__ rp,
                                               int N, int E, int NBUK) {
    __shared__ int s[512];
    int tid = threadIdx.x;
    int v = (tid < NBUK) ? (gcur[tid] - tid * RCAP) : 0;
    s[tid] = v;
    __syncthreads();
    for (int o = 1; o < 512; o <<= 1) {
        int t = (tid >= o) ? s[tid - o] : 0;
        __syncthreads();
        s[tid] += t;
        __syncthreads();
    }
    if (tid < NBUK) { gbase[tid] = s[tid] - v; gcnt[tid] = v; }
    if (tid == 0) rp[N] = E;
}

// ---------------- per-bucket sort by dst; region -> dense csr ---------------
__global__ __launch_bounds__(512) void k_fillB(const u32* __restrict__ part,
                                               const int* __restrict__ gbase,
                                               const int* __restrict__ gcnt,
                                               u32* __restrict__ csr,
                                               int* __restrict__ rp,
                                               float* __restrict__ dinv, int N) {
    __shared__ int hist[256];
    __shared__ int ofs[256];
    __shared__ u32 srcbuf[CAP];
    int b = blockIdx.x, tid = threadIdx.x;
    int base_r = b * RCAP;                 // read from region
    int base_w = gbase[b];                 // write dense
    int cnt = gcnt[b];
    if (tid < 256) hist[tid] = 0;
    __syncthreads();
    for (int j = tid; j < cnt; j += 512)
        atomicAdd(&hist[part[base_r + j] >> 24], 1);
    __syncthreads();
    int v = 0;
    if (tid < 256) { v = hist[tid]; ofs[tid] = v; }
    __syncthreads();
    for (int o = 1; o < 256; o <<= 1) {
        int t = 0;
        if (tid < 256 && tid >= o) t = ofs[tid - o];
        __syncthreads();
        if (tid < 256) ofs[tid] += t;
        __syncthreads();
    }
    int excl = 0;
    if (tid < 256) { excl = ofs[tid] - v; hist[tid] = excl; }
    __syncthreads();
    for (int j = tid; j < cnt; j += 512) {
        u32 pv = part[base_r + j];
        int pos = atomicAdd(&hist[pv >> 24], 1);
        if (pos < CAP) srcbuf[pos] = pv & 0xFFFFFFu;
    }
    __syncthreads();
    for (int j = tid; j < cnt; j += 512)
        csr[base_w + j] = srcbuf[j];       // coalesced dense write
    int d = b * 256 + tid;
    if (tid < 256 && d < N) {
        rp[d] = base_w + excl;
        dinv[d] = rsqrtf((float)(v + 1));  // +1 self loop
    }
}

// ---------------- hs[N,16](bf16) = (x@W1)*dinv, K-split, x read once ---------
__global__ __launch_bounds__(256) void k_xw1(const float* __restrict__ x,
                                             const float* __restrict__ W1,
                                             const float* __restrict__ dinv,
                                             u16* __restrict__ hs, int N) {
    __shared__ float w[4 * 516];   // section q = W1 rows 32q..32q+31; +4 pad
    int tid = threadIdx.x;
    for (int t = tid; t < 2048; t += 256)
        w[(t >> 9) * 516 + (t & 511)] = W1[t];
    __syncthreads();
    int t = blockIdx.x * 256 + tid;
    int n = t >> 2, q = t & 3;
    if (n >= N) return;
    const float4* xr = (const float4*)(x + (size_t)n * 128 + q * 32);  // 8 f4
    const float* ws = w + q * 516;
    float acc[16];
    #pragma unroll
    for (int c = 0; c < 16; ++c) acc[c] = 0.f;
    #pragma unroll
    for (int i = 0; i < 8; ++i) {
        float4 u = xr[i];
        const float4* wf = (const float4*)(ws + i * 64);  // rows 4i..4i+3
        #pragma unroll
        for (int c4 = 0; c4 < 4; ++c4) {
            float4 wa = wf[c4];
            float4 wb = wf[4 + c4];
            float4 wc = wf[8 + c4];
            float4 wd = wf[12 + c4];
            int c = c4 * 4;
            acc[c+0] = fmaf(u.x, wa.x, acc[c+0]); acc[c+1] = fmaf(u.x, wa.y, acc[c+1]);
            acc[c+2] = fmaf(u.x, wa.z, acc[c+2]); acc[c+3] = fmaf(u.x, wa.w, acc[c+3]);
            acc[c+0] = fmaf(u.y, wb.x, acc[c+0]); acc[c+1] = fmaf(u.y, wb.y, acc[c+1]);
            acc[c+2] = fmaf(u.y, wb.z, acc[c+2]); acc[c+3] = fmaf(u.y, wb.w, acc[c+3]);
            acc[c+0] = fmaf(u.z, wc.x, acc[c+0]); acc[c+1] = fmaf(u.z, wc.y, acc[c+1]);
            acc[c+2] = fmaf(u.z, wc.z, acc[c+2]); acc[c+3] = fmaf(u.z, wc.w, acc[c+3]);
            acc[c+0] = fmaf(u.w, wd.x, acc[c+0]); acc[c+1] = fmaf(u.w, wd.y, acc[c+1]);
            acc[c+2] = fmaf(u.w, wd.z, acc[c+2]); acc[c+3] = fmaf(u.w, wd.w, acc[c+3]);
        }
    }
    #pragma unroll
    for (int c = 0; c < 16; ++c) {
        acc[c] += __shfl_xor(acc[c], 1);
        acc[c] += __shfl_xor(acc[c], 2);
    }
    float di = dinv[n];
    uint2 o;
    o.x = pack_bf2(acc[4*q+0] * di, acc[4*q+1] * di);
    o.y = pack_bf2(acc[4*q+2] * di, acc[4*q+3] * di);
    ((uint2*)(hs + (size_t)n * 16))[q] = o;
}

// ---------------- fused layer-1 gather + ReLU + W2 projection ----------------
// 4 nodes/wave; 16 lanes/node = 2 halves (16B uint4 each) x 8 edge groups.
__global__ __launch_bounds__(256) void k_agg1h2(const int* __restrict__ rp,
                                                const int* __restrict__ csr,
                                                const u16* __restrict__ hs,
                                                const float* __restrict__ dinv,
                                                const float* __restrict__ W2,
                                                const float* __restrict__ b1,
                                                float* __restrict__ h2s, int N) {
    int lane = threadIdx.x & 63;
    int wid = blockIdx.x * 16 + (threadIdx.x >> 6) * 4 + (lane >> 4);
    if (wid >= N) return;
    int l = lane & 15;
    int half = l & 1, g = l >> 1;                  // 16B half, edge group
    int beg = rp[wid], end = rp[wid + 1];
    float a0 = 0.f, a1 = 0.f, a2 = 0.f, a3 = 0.f;
    float a4 = 0.f, a5 = 0.f, a6 = 0.f, a7 = 0.f;
    for (int j = beg + g; j < end; j += 8) {
        int s = csr[j];
        uint4 u = ((const uint4*)(hs + (size_t)s * 16))[half];
        a0 += bflo(u.x); a1 += bfhi(u.x);
        a2 += bflo(u.y); a3 += bfhi(u.y);
        a4 += bflo(u.z); a5 += bfhi(u.z);
        a6 += bflo(u.w); a7 += bfhi(u.w);
    }
    a0 += __shfl_xor(a0, 2); a1 += __shfl_xor(a1, 2);
    a2 += __shfl_xor(a2, 2); a3 += __shfl_xor(a3, 2);
    a4 += __shfl_xor(a4, 2); a5 += __shfl_xor(a5, 2);
    a6 += __shfl_xor(a6, 2); a7 += __shfl_xor(a7, 2);
    a0 += __shfl_xor(a0, 4); a1 += __shfl_xor(a1, 4);
    a2 += __shfl_xor(a2, 4); a3 += __shfl_xor(a3, 4);
    a4 += __shfl_xor(a4, 4); a5 += __shfl_xor(a5, 4);
    a6 += __shfl_xor(a6, 4); a7 += __shfl_xor(a7, 4);
    a0 += __shfl_xor(a0, 8); a1 += __shfl_xor(a1, 8);
    a2 += __shfl_xor(a2, 8); a3 += __shfl_xor(a3, 8);
    a4 += __shfl_xor(a4, 8); a5 += __shfl_xor(a5, 8);
    a6 += __shfl_xor(a6, 8); a7 += __shfl_xor(a7, 8);
    uint4 su = ((const uint4*)(hs + (size_t)wid * 16))[half];   // self term
    a0 += bflo(su.x); a1 += bfhi(su.x);
    a2 += bflo(su.y); a3 += bfhi(su.y);
    a4 += bflo(su.z); a5 += bfhi(su.z);
    a6 += bflo(su.w); a7 += bfhi(su.w);
    float di = dinv[wid];
    float4 bA = ((const float4*)b1)[half * 2];
    float4 bB = ((const float4*)b1)[half * 2 + 1];
    float v0 = fmaxf(fmaf(di, a0, bA.x), 0.f);
    float v1 = fmaxf(fmaf(di, a1, bA.y), 0.f);
    float v2 = fmaxf(fmaf(di, a2, bA.z), 0.f);
    float v3 = fmaxf(fmaf(di, a3, bA.w), 0.f);
    float v4 = fmaxf(fmaf(di, a4, bB.x), 0.f);
    float v5 = fmaxf(fmaf(di, a5, bB.y), 0.f);
    float v6 = fmaxf(fmaf(di, a6, bB.z), 0.f);
    float v7 = fmaxf(fmaf(di, a7, bB.w), 0.f);
    const float4* w4 = (const float4*)W2 + half * 4;   // rows half*8..+7
    float4 q0 = w4[0], q1 = w4[1], q2 = w4[2], q3 = w4[3];
    float p0 = v0*q0.x + v1*q0.z + v2*q1.x + v3*q1.z
             + v4*q2.x + v5*q2.z + v6*q3.x + v7*q3.z;
    float p1 = v0*q0.y + v1*q0.w + v2*q1.y + v3*q1.w
             + v4*q2.y + v5*q2.w + v6*q3.y + v7*q3.w;
    p0 += __shfl_xor(p0, 1); p1 += __shfl_xor(p1, 1);  // sum the two halves
    if (l == 0)
        *(float2*)(h2s + (size_t)wid * 2) = make_float2(p0 * di, p1 * di);
}

// ---------------- layer-2 gather -> out (4 nodes/wave, 16 lanes/node) --------
__global__ __launch_bounds__(256) void k_agg2(const int* __restrict__ rp,
                                              const int* __restrict__ csr,
                                              const float* __restrict__ h2s,
                                              const float* __restrict__ dinv,
                                              const float* __restrict__ b2,
                                              float* __restrict__ out, int N) {
    int lane = threadIdx.x & 63;
    int wid = blockIdx.x * 16 + (threadIdx.x >> 6) * 4 + (lane >> 4);
    if (wid >= N) return;
    int l = lane & 15;
    int beg = rp[wid], end = rp[wid + 1];
    float a0 = 0.f, a1 = 0.f;
    for (int j = beg + l; j < end; j += 16) {
        int s = csr[j];
        float2 v = *(const float2*)(h2s + (size_t)s * 2);
        a0 += v.x; a1 += v.y;
    }
    a0 += __shfl_xor(a0, 1); a1 += __shfl_xor(a1, 1);
    a0 += __shfl_xor(a0, 2); a1 += __shfl_xor(a1, 2);
    a0 += __shfl_xor(a0, 4); a1 += __shfl_xor(a1, 4);
    a0 += __shfl_xor(a0, 8); a1 += __shfl_xor(a1, 8);
    if (l == 0) {
        float di = dinv[wid];
        float2 sv = *(const float2*)(h2s + (size_t)wid * 2);
        *(float2*)(out + (size_t)wid * 2) =
            make_float2(fmaf(di, a0 + sv.x, b2[0]), fmaf(di, a1 + sv.y, b2[1]));
    }
}

extern "C" void kernel_launch(void* const* d_in, const int* in_sizes, int n_in,
                              void* d_out, int out_size, void* d_ws, size_t ws_size,
                              hipStream_t stream) {
    const float* x  = (const float*)d_in[0];
    const int*   ei = (const int*)d_in[1];
    const float* W1 = (const float*)d_in[2];
    const float* b1 = (const float*)d_in[3];
    const float* W2 = (const float*)d_in[4];
    const float* b2 = (const float*)d_in[5];
    float* out = (float*)d_out;

    const int N = in_sizes[0] / 128;      // 100000
    const int E = in_sizes[1] / 2;        // 3200000
    const int NBUK = (N + 255) / 256;     // 391 (<= 512)
    const int NPB  = (E + EPB - 1) / EPB; // 391

    char* ws = (char*)d_ws;
    size_t off = 0;
    auto alloc = [&](size_t bytes) {
        void* p = ws + off;
        off = (off + bytes + 255) & ~(size_t)255;
        return p;
    };
    u32*   part  = (u32*)alloc((size_t)NBUK * RCAP * 4); // strided regions
    u32*   csr   = (u32*)alloc((size_t)E * 4);           // dense sorted
    int*   rp    = (int*)alloc((size_t)(N + 1) * 4);
    float* dinv  = (float*)alloc((size_t)N * 4);
    u16*   hs    = (u16*)alloc((size_t)N * 16 * 2);      // bf16
    float* h2s   = (float*)alloc((size_t)N * 2 * 4);
    int*   gcnt  = (int*)alloc((size_t)NBUK * 4);
    int*   gbase = (int*)alloc((size_t)NBUK * 4);
    int*   gcur  = (int*)alloc((size_t)NBUK * 4);

    k_binit  <<<dim3(1),    dim3(512), 0, stream>>>(gcur, NBUK);
    k_scatter<<<dim3(NPB),  dim3(512), 0, stream>>>(ei, gcur, part, E, NBUK);
    k_bscan  <<<dim3(1),    dim3(512), 0, stream>>>(gcur, gcnt, gbase, rp, N, E, NBUK);
    k_fillB  <<<dim3(NBUK), dim3(512), 0, stream>>>(part, gbase, gcnt, csr, rp, dinv, N);
    k_xw1    <<<dim3((N * 4 + 255) / 256), dim3(256), 0, stream>>>(x, W1, dinv, hs, N);
    k_agg1h2 <<<dim3((N + 15) / 16), dim3(256), 0, stream>>>(rp, (const int*)csr, hs, dinv, W2, b1, h2s, N);
    k_agg2   <<<dim3((N + 15) / 16), dim3(256), 0, stream>>>(rp, (const int*)csr, h2s, dinv, b2, out, N);
}